// Round 15
// baseline (172.471 us; speedup 1.0000x reference)
//
#include <hip/hip_runtime.h>
#include <math.h>

#define LQ 2048
#define EQ 1024
#define HQ 1024
#define DQ 512
#define VQ 32000
#define MVQ 32768

// d_out layout (floats): [out1: 32768][h_new: 1024][attn_w: 2048][prob_c: 2048]
#define OUT1_OFF 0
#define HNEW_OFF 32768
#define AW_OFF   33792
#define PC_OFF   35840

typedef __attribute__((ext_vector_type(8))) short short8_t;
typedef __attribute__((ext_vector_type(8))) unsigned short ushort8_t;
typedef __attribute__((ext_vector_type(4))) float floatx4;

// ---------------- helpers ----------------
__device__ inline float wred(float v) {
    v += __shfl_down(v, 32);
    v += __shfl_down(v, 16);
    v += __shfl_down(v, 8);
    v += __shfl_down(v, 4);
    v += __shfl_down(v, 2);
    v += __shfl_down(v, 1);
    return v;
}
__device__ inline float wred_max(float v) {
    v = fmaxf(v, __shfl_down(v, 32));
    v = fmaxf(v, __shfl_down(v, 16));
    v = fmaxf(v, __shfl_down(v, 8));
    v = fmaxf(v, __shfl_down(v, 4));
    v = fmaxf(v, __shfl_down(v, 2));
    v = fmaxf(v, __shfl_down(v, 1));
    return v;
}
__device__ inline float sigmoidf_(float x) { return 1.0f / (1.0f + expf(-x)); }
__device__ inline unsigned short f2bf(float x) {  // RNE to bf16 bits
    unsigned int u = __float_as_uint(x);
    unsigned int r = (u + 0x7fffu + ((u >> 16) & 1u)) >> 16;
    return (unsigned short)r;
}
__device__ inline float bf2f(unsigned short b) {
    return __uint_as_float(((unsigned int)b) << 16);
}
// async global->LDS, 16B per lane; LDS dest is wave-uniform base + lane*16
__device__ __forceinline__ void gload16(const unsigned short* g,
                                        unsigned short* l) {
    __builtin_amdgcn_global_load_lds(
        (const __attribute__((address_space(1))) unsigned int*)g,
        (__attribute__((address_space(3))) unsigned int*)l, 16, 0, 0);
}

// ---------------- k_prep ----------------
// blocks 0..511   : attn logits (4 rows/block); blocks 0..3 also zero aa
// block  512      : sel_reading (exact int32 truncation) -> x2[1024:2048)
// blocks 513..2048: split enc (2M) then Wc (1M) into bf16 hi/lo
__global__ __launch_bounds__(256) void k_prep(
    const float* __restrict__ enc, const float* __restrict__ Wc,
    const int* __restrict__ inp, const int* __restrict__ input_seq,
    const int* __restrict__ pre_prob,
    const float* __restrict__ attn_W, const float* __restrict__ attn_b,
    const float* __restrict__ emb, const float* __restrict__ hidden,
    unsigned short* __restrict__ Ah, unsigned short* __restrict__ Al,
    unsigned short* __restrict__ Bh, unsigned short* __restrict__ Bl,
    float* __restrict__ x2, float* __restrict__ logits, float* __restrict__ aa)
{
    __shared__ int s_cnt;
    __shared__ int s_list[LQ];
    const int tid = threadIdx.x;
    const int bx = blockIdx.x;
    if (bx < 512) {  // ---- attn logits ----
        if (bx < 4) aa[bx * 256 + tid] = 0.0f;
        int warp = tid >> 6, lane = tid & 63;
        int r = bx * 4 + warp;
        int tok = inp[0];
        int ei = (tok >= VQ) ? 2 : tok;
        const float4* Wr = (const float4*)(attn_W + (size_t)r * 1536);
        const float4* e4 = (const float4*)(emb + (size_t)ei * DQ);
        const float4* h4 = (const float4*)hidden;
        float acc = 0.0f;
        #pragma unroll
        for (int i = 0; i < 6; ++i) {
            int idx = lane + i * 64;
            float4 x = (idx < 128) ? e4[idx] : h4[idx - 128];
            float4 w = Wr[idx];
            acc += w.x * x.x + w.y * x.y + w.z * x.z + w.w * x.w;
        }
        acc = wred(acc);
        if (lane == 0) logits[r] = acc + attn_b[r];
        return;
    }
    if (bx == 512) {  // ---- sel_reading ----
        if (tid == 0) s_cnt = 0;
        __syncthreads();
        int tok = inp[0];
        for (int l = tid; l < LQ; l += 256) {
            if (input_seq[l] == tok && pre_prob[l] != 0) {
                int p = atomicAdd(&s_cnt, 1);
                s_list[p] = l;
            }
        }
        __syncthreads();
        int nm = s_cnt;
        for (int e = tid; e < EQ; e += 256) {
            int acc = 0;
            for (int j = 0; j < nm; ++j)
                acc += (int)enc[(size_t)s_list[j] * EQ + e];
            x2[HQ + e] = (float)acc;
        }
        return;
    }
    // ---- bf16 hi/lo split ----
    size_t e0 = ((size_t)(bx - 513) * 256 + tid) * 8;
    const float* src;
    unsigned short *hdst, *ldst;
    size_t off;
    if (e0 < (size_t)LQ * EQ) { src = enc; hdst = Ah; ldst = Al; off = e0; }
    else { src = Wc; hdst = Bh; ldst = Bl; off = e0 - (size_t)LQ * EQ; }
    float4 v0 = *(const float4*)(src + off);
    float4 v1 = *(const float4*)(src + off + 4);
    float vv[8] = {v0.x, v0.y, v0.z, v0.w, v1.x, v1.y, v1.z, v1.w};
    ushort8_t H, L;
    #pragma unroll
    for (int k = 0; k < 8; ++k) {
        float x = vv[k];
        unsigned short hb = f2bf(x);
        H[k] = hb;
        L[k] = f2bf(x - bf2f(hb));  // exact residual
    }
    *(ushort8_t*)(hdst + off) = H;
    *(ushort8_t*)(ldst + off) = L;
}

// ---------------- k_gemm_fused ----------------
// DIAGNOSTIC ROUND (6x): GEMM branch repeats its full K-loop 6 times
// (commit on last rep only; non-final accumulators kept live via asm
// sinks). Output identical; gemm-block dispatch time ~= 6 * t_gemm so it
// is GUARANTEED visible in the top-5 counter table under both models,
// and Delta(total) = 5 * t_gemm.
// blocks [0,512)     : T[l][h] = tanh(enc[l,:].Wc[h,:] + Wc_b[h])
// blocks [512,576)   : attn softmax + apply -> aa (+ aw output)
// blocks [576,1344)  : gi_sel[r] = W_ih[r,1024:2048] . sel       (3072 rows)
// blocks [1344,2112) : gh_pre[r] = W_hh[r,:] . hidden            (3072 rows)
// blocks [2112,2368) : pre_c[r]  = comb_W[r,0:512] . emb_row     (1024 rows)
__global__ __launch_bounds__(256, 2) void k_gemm_fused(
    const unsigned short* __restrict__ Ah, const unsigned short* __restrict__ Al,
    const unsigned short* __restrict__ Bh, const unsigned short* __restrict__ Bl,
    float* __restrict__ T, const float* __restrict__ Wc_b,
    const float* __restrict__ logits, const float* __restrict__ enc,
    float* __restrict__ aa, float* __restrict__ aw_out,
    const float* __restrict__ W_ih, const float* __restrict__ W_hh,
    const float* __restrict__ comb_W, const int* __restrict__ inp,
    const float* __restrict__ emb, const float* __restrict__ hidden,
    const float* __restrict__ x2,
    float* __restrict__ gi_sel, float* __restrict__ gh_pre,
    float* __restrict__ pre_c)
{
    // 2 buffers x 4 arrays x 64 rows x 64 bf16 = 64 KB -> 2 blocks/CU
    __shared__ unsigned short sm[2 * 4 * 4096];
    const int b = blockIdx.x, t = threadIdx.x;
    const int lane = t & 63, wid = t >> 6;

    if (b < 512) {  // =================== GEMM -> T ===================
        const int n0 = (b & 15) * 64;    // 16 col-tiles
        const int m0 = (b >> 4) * 64;    // 32 row-tiles
        const unsigned short* tsrc =
            (wid == 0) ? Ah + (size_t)m0 * EQ :
            (wid == 1) ? Al + (size_t)m0 * EQ :
            (wid == 2) ? Bh + (size_t)n0 * EQ :
                         Bl + (size_t)n0 * EQ;
        const int srow = lane >> 3;     // 0..7: row within 8-row call
        const int schunk = lane & 7;    // 0..7: 16B chunk within 128B row
        const int gch = schunk ^ srow;  // source-side swizzle (row&7 == srow)
        const int wm = (wid >> 1) * 32, wn = (wid & 1) * 32;
        const int fr = lane & 15, kg = lane >> 4;

        floatx4 acc[2][2];

        #define STAGE(buf, s)                                                  \
            {                                                                  \
                unsigned short* dst = sm + (buf) * 16384 + wid * 4096;         \
                _Pragma("unroll")                                              \
                for (int c = 0; c < 8; ++c) {                                  \
                    int row = c * 8 + srow;                                    \
                    gload16(tsrc + (size_t)row * EQ + (s) * 64 + gch * 8,      \
                            dst + c * 512);                                    \
                }                                                              \
            }

        for (int rep = 0; rep < 6; ++rep) {
            #pragma unroll
            for (int i = 0; i < 2; ++i)
                #pragma unroll
                for (int j = 0; j < 2; ++j)
                    acc[i][j] = (floatx4){0.f, 0.f, 0.f, 0.f};

            STAGE(0, 0);
            __syncthreads();  // vmcnt(0) drain by compiler
            for (int s = 0; s < 16; ++s) {
                int cur = s & 1;
                if (s < 15) STAGE(cur ^ 1, s + 1);  // async under compute
                const char* base = (const char*)sm + cur * 32768;
                #pragma unroll
                for (int kk = 0; kk < 2; ++kk) {
                    short8_t fah[2], fal[2], fbh[2], fbl[2];
                    #pragma unroll
                    for (int f = 0; f < 2; ++f) {
                        int ra = wm + f * 16 + fr;
                        int oa = ra * 128 + (((kk * 4 + kg) ^ (ra & 7)) * 16);
                        fah[f] = *(const short8_t*)(base + oa);
                        fal[f] = *(const short8_t*)(base + 8192 + oa);
                        int rb = wn + f * 16 + fr;
                        int ob = rb * 128 + (((kk * 4 + kg) ^ (rb & 7)) * 16);
                        fbh[f] = *(const short8_t*)(base + 16384 + ob);
                        fbl[f] = *(const short8_t*)(base + 24576 + ob);
                    }
                    #pragma unroll
                    for (int i = 0; i < 2; ++i)
                        #pragma unroll
                        for (int j = 0; j < 2; ++j) {
                            acc[i][j] = __builtin_amdgcn_mfma_f32_16x16x32_bf16(
                                fah[i], fbh[j], acc[i][j], 0, 0, 0);
                            acc[i][j] = __builtin_amdgcn_mfma_f32_16x16x32_bf16(
                                fal[i], fbh[j], acc[i][j], 0, 0, 0);
                            acc[i][j] = __builtin_amdgcn_mfma_f32_16x16x32_bf16(
                                fah[i], fbl[j], acc[i][j], 0, 0, 0);
                        }
                }
                __syncthreads();  // drains next-stage loads, guards reuse
            }
            if (rep < 5) {
                // keep non-final accumulators live (anti-DCE, rule #17)
                #pragma unroll
                for (int i = 0; i < 2; ++i)
                    #pragma unroll
                    for (int j = 0; j < 2; ++j)
                        #pragma unroll
                        for (int r = 0; r < 4; ++r)
                            asm volatile("" :: "v"(acc[i][j][r]));
            }
        }
        // epilogue: tanh(acc + bias) -> T.  C/D: col=lane&15, row=(lane>>4)*4+r
        #pragma unroll
        for (int i = 0; i < 2; ++i)
            #pragma unroll
            for (int j = 0; j < 2; ++j) {
                int row = m0 + wm + i * 16 + kg * 4;
                int col = n0 + wn + j * 16 + fr;
                float bj = Wc_b[col];
                #pragma unroll
                for (int r = 0; r < 4; ++r)
                    T[(size_t)(row + r) * HQ + col] = tanhf(acc[i][j][r] + bj);
            }
        return;
    }
    if (b < 576) {  // =============== attn softmax + apply ===============
        float* sred = (float*)sm;        // alias onto gemm LDS
        float* s_w  = (float*)sm + 8;
        int sb = b - 512;
        int xb = sb & 3, yb = sb >> 2;
        float m = -3.4e38f;
        for (int i = t; i < LQ; i += 256) m = fmaxf(m, logits[i]);
        m = wred_max(m);
        if (lane == 0) sred[wid] = m;
        __syncthreads();
        if (t == 0)
            sred[0] = fmaxf(fmaxf(sred[0], sred[1]), fmaxf(sred[2], sred[3]));
        __syncthreads();
        m = sred[0];
        __syncthreads();
        float s = 0.0f;
        for (int i = t; i < LQ; i += 256) s += expf(logits[i] - m);
        s = wred(s);
        if (lane == 0) sred[wid] = s;
        __syncthreads();
        if (t == 0) sred[0] = sred[0] + sred[1] + sred[2] + sred[3];
        __syncthreads();
        s = sred[0];
        int l0 = yb * 128;
        if (t < 128) {
            float w = expf(logits[l0 + t] - m) / s;
            s_w[t] = w;
            if (xb == 0) aw_out[l0 + t] = w;
        }
        __syncthreads();
        int e = xb * 256 + t;
        float acc = 0.0f;
        for (int l = 0; l < 128; ++l)
            acc = fmaf(s_w[l], enc[(size_t)(l0 + l) * EQ + e], acc);
        atomicAdd(&aa[e], acc);
        return;
    }
    if (b < 1344) {  // =============== gi_sel ===============
        int row = (b - 576) * 4 + wid;  // [0, 3072)
        const float4* Wr = (const float4*)(W_ih + (size_t)row * 2048 + 1024);
        const float4* xs = (const float4*)(x2 + HQ);
        float acc = 0.0f;
        #pragma unroll
        for (int c = 0; c < 4; ++c) {
            int idx = lane + c * 64;
            float4 w = Wr[idx], x = xs[idx];
            acc += w.x * x.x + w.y * x.y + w.z * x.z + w.w * x.w;
        }
        acc = wred(acc);
        if (lane == 0) gi_sel[row] = acc;
        return;
    }
    if (b < 2112) {  // =============== gh_pre ===============
        int row = (b - 1344) * 4 + wid;  // [0, 3072)
        const float4* Wr = (const float4*)(W_hh + (size_t)row * 1024);
        const float4* hv = (const float4*)hidden;
        float acc = 0.0f;
        #pragma unroll
        for (int c = 0; c < 4; ++c) {
            int idx = lane + c * 64;
            float4 w = Wr[idx], x = hv[idx];
            acc += w.x * x.x + w.y * x.y + w.z * x.z + w.w * x.w;
        }
        acc = wred(acc);
        if (lane == 0) gh_pre[row] = acc;
        return;
    }
    {  // =============== pre_c (comb embedded half) ===============
        int row = (b - 2112) * 4 + wid;  // [0, 1024)
        int tok = inp[0];
        int ei = (tok >= VQ) ? 2 : tok;
        const float4* Wr = (const float4*)(comb_W + (size_t)row * 1536);
        const float4* e4 = (const float4*)(emb + (size_t)ei * DQ);
        float acc = 0.0f;
        #pragma unroll
        for (int c = 0; c < 2; ++c) {
            int idx = lane + c * 64;
            float4 w = Wr[idx], x = e4[idx];
            acc += w.x * x.x + w.y * x.y + w.z * x.z + w.w * x.w;
        }
        acc = wred(acc);
        if (lane == 0) pre_c[row] = acc;
        return;
    }
}

// ---------------- k_comb ----------------
// x2[r] = relu(pre_c[r] + comb_W[r,512:1536].aa + comb_b[r])
__global__ __launch_bounds__(256) void k_comb(
    const float* __restrict__ W, const float* __restrict__ b,
    const float* __restrict__ pre_c, const float* __restrict__ aa,
    float* __restrict__ x2)
{
    int warp = threadIdx.x >> 6, lane = threadIdx.x & 63;
    int r = blockIdx.x * 4 + warp;
    const float4* Wr = (const float4*)(W + (size_t)r * 1536 + 512);
    const float4* a4 = (const float4*)aa;
    float acc = 0.0f;
    #pragma unroll
    for (int i = 0; i < 4; ++i) {
        int idx = lane + i * 64;
        float4 w = Wr[idx], x = a4[idx];
        acc += w.x * x.x + w.y * x.y + w.z * x.z + w.w * x.w;
    }
    acc = wred(acc);
    if (lane == 0) x2[r] = fmaxf(acc + pre_c[r] + b[r], 0.0f);
}

// ---------------- k_gru ----------------
// Wave per gate index i: dot the comb-half of the 3 W_ih rows; add
// precomputed gi_sel / gh_pre; gates; h_new.
__global__ __launch_bounds__(256) void k_gru(
    const float* __restrict__ W_ih, const float* __restrict__ gi_sel,
    const float* __restrict__ gh_pre,
    const float* __restrict__ b_ih, const float* __restrict__ b_hh,
    const float* __restrict__ x2, const float* __restrict__ h,
    float* __restrict__ hnew, float* __restrict__ out_h)
{
    int warp = threadIdx.x >> 6, lane = threadIdx.x & 63;
    int i = blockIdx.x * 4 + warp;
    const float4* xv = (const float4*)x2;
    const float4* Wr = (const float4*)(W_ih + (size_t)i * 2048);
    const float4* Wz = (const float4*)(W_ih + (size_t)(HQ + i) * 2048);
    const float4* Wn = (const float4*)(W_ih + (size_t)(2 * HQ + i) * 2048);
    float ar = 0, az = 0, an = 0;
    #pragma unroll
    for (int c = 0; c < 4; ++c) {
        int idx = lane + c * 64;
        float4 x = xv[idx];
        float4 w = Wr[idx]; ar += w.x*x.x + w.y*x.y + w.z*x.z + w.w*x.w;
        w = Wz[idx];        az += w.x*x.x + w.y*x.y + w.z*x.z + w.w*x.w;
        w = Wn[idx];        an += w.x*x.x + w.y*x.y + w.z*x.z + w.w*x.w;
    }
    ar = wred(ar); az = wred(az); an = wred(an);
    if (lane == 0) {
        float gir = ar + gi_sel[i] + b_ih[i];
        float giz = az + gi_sel[HQ + i] + b_ih[HQ + i];
        float gin = an + gi_sel[2 * HQ + i] + b_ih[2 * HQ + i];
        float ghr = gh_pre[i] + b_hh[i];
        float ghz = gh_pre[HQ + i] + b_hh[HQ + i];
        float ghn = gh_pre[2 * HQ + i] + b_hh[2 * HQ + i];
        float r = sigmoidf_(gir + ghr);
        float z = sigmoidf_(giz + ghz);
        float n = tanhf(gin + r * ghn);
        float hn = (1.0f - z) * n + z * h[i];
        hnew[i] = hn;
        out_h[i] = hn;
    }
}

// ---------------- k_scores ----------------
// Unified: r < VQ rows come from Wo_W (+bias), r >= VQ rows come from T
// (tanh already applied in the gemm epilogue). One wave per row.
__global__ __launch_bounds__(256) void k_scores(
    const float* __restrict__ Wo_W, const float* __restrict__ Wo_b,
    const float* __restrict__ T, const float* __restrict__ hnew,
    float* __restrict__ score)
{
    int warp = threadIdx.x >> 6, lane = threadIdx.x & 63;
    int r = blockIdx.x * 4 + warp;
    const float4* hv = (const float4*)hnew;
    const float* Wr = (r < VQ) ? Wo_W + (size_t)r * HQ
                               : T + (size_t)(r - VQ) * HQ;
    const float4* W4 = (const float4*)Wr;
    float acc = 0.0f;
    #pragma unroll
    for (int i = 0; i < 4; ++i) {
        int idx = lane + i * 64;
        float4 w = W4[idx], x = hv[idx];
        acc += w.x * x.x + w.y * x.y + w.z * x.z + w.w * x.w;
    }
    acc = wred(acc);
    if (lane == 0) score[r] = acc + ((r < VQ) ? Wo_b[r] : 0.0f);
}

// ---------------- k_final ----------------
// 128 blocks: per-block recompute of softmax stats (deterministic), LDS-bin
// scatter for the block's 256-wide out1 slice, then log with 1e-9 rules.
__global__ __launch_bounds__(256) void k_final(
    const float* __restrict__ score, const int* __restrict__ input_seq,
    float* __restrict__ out1, float* __restrict__ out_pc)
{
    __shared__ float sred[4];
    __shared__ float bins[256];
    const int N = VQ + LQ;
    int tid = threadIdx.x, wid = tid >> 6, lane = tid & 63;
    float m = -3.4e38f;
    for (int i = tid; i < N; i += 256) m = fmaxf(m, score[i]);
    m = wred_max(m);
    if (lane == 0) sred[wid] = m;
    __syncthreads();
    if (tid == 0)
        sred[0] = fmaxf(fmaxf(sred[0], sred[1]), fmaxf(sred[2], sred[3]));
    __syncthreads();
    m = sred[0];
    __syncthreads();
    float s = 0.0f;
    for (int i = tid; i < N; i += 256) s += expf(score[i] - m);
    s = wred(s);
    if (lane == 0) sred[wid] = s;
    __syncthreads();
    if (tid == 0) sred[0] = sred[0] + sred[1] + sred[2] + sred[3];
    __syncthreads();
    s = sred[0];
    bins[tid] = 0.0f;
    __syncthreads();
    int i0 = blockIdx.x * 256;
    for (int l = tid; l < LQ; l += 256) {
        int si = input_seq[l];
        if (si >= i0 && si < i0 + 256)
            atomicAdd(&bins[si - i0], expf(score[VQ + l] - m) / s);
    }
    if (blockIdx.x < 8) {
        int l = blockIdx.x * 256 + tid;
        out_pc[l] = expf(score[VQ + l] - m) / s;
    }
    __syncthreads();
    int i = i0 + tid;
    float v = ((i < VQ) ? expf(score[i] - m) / s : 0.0f) + bins[tid];
    if (i == 2 || v == 0.0f) v = 1e-9f;
    out1[i] = logf(v);
}

// ---------------- host launch ----------------
extern "C" void kernel_launch(void* const* d_in, const int* in_sizes, int n_in,
                              void* d_out, int out_size, void* d_ws, size_t ws_size,
                              hipStream_t stream) {
    const int*   inp       = (const int*)  d_in[0];
    const float* hidden    = (const float*)d_in[1];
    const float* enc       = (const float*)d_in[2];
    const int*   input_seq = (const int*)  d_in[3];
    const int*   pre_prob  = (const int*)  d_in[4];
    const float* emb       = (const float*)d_in[5];
    const float* attn_W    = (const float*)d_in[6];
    const float* attn_b    = (const float*)d_in[7];
    const float* comb_W    = (const float*)d_in[8];
    const float* comb_b    = (const float*)d_in[9];
    const float* W_ih      = (const float*)d_in[10];
    const float* W_hh      = (const float*)d_in[11];
    const float* b_ih      = (const float*)d_in[12];
    const float* b_hh      = (const float*)d_in[13];
    const float* Wo_W      = (const float*)d_in[14];
    const float* Wo_b      = (const float*)d_in[15];
    const float* Wc_W      = (const float*)d_in[16];
    const float* Wc_b      = (const float*)d_in[17];

    float* out = (float*)d_out;

    // ws: [Ah 2M us][Al 2M us][Bh 1M us][Bl 1M us][T 2M f][smalls]
    unsigned short* Ah = (unsigned short*)d_ws;
    unsigned short* Al = Ah + (size_t)LQ * EQ;
    unsigned short* Bh = Al + (size_t)LQ * EQ;
    unsigned short* Bl = Bh + (size_t)HQ * EQ;
    float* T      = (float*)(Bl + (size_t)HQ * EQ);
    float* x2     = T + (size_t)LQ * HQ;       // 2048 (comb out | sel_reading)
    float* hnew   = x2 + 2048;                 // 1024
    float* logits = hnew + 1024;               // 2048
    float* aa     = logits + 2048;             // 1024
    float* score  = aa + 1024;                 // 34048
    float* gi_sel = score + 34048;             // 3072
    float* gh_pre = gi_sel + 3072;             // 3072
    float* pre_c  = gh_pre + 3072;             // 1024

    k_prep<<<2049, 256, 0, stream>>>(enc, Wc_W, inp, input_seq, pre_prob,
                                     attn_W, attn_b, emb, hidden,
                                     Ah, Al, Bh, Bl, x2, logits, aa);
    k_gemm_fused<<<2368, 256, 0, stream>>>(Ah, Al, Bh, Bl, T, Wc_b, logits,
                                           enc, aa, out + AW_OFF, W_ih, W_hh,
                                           comb_W, inp, emb, hidden, x2,
                                           gi_sel, gh_pre, pre_c);
    k_comb<<<HQ / 4, 256, 0, stream>>>(comb_W, comb_b, pre_c, aa, x2);
    k_gru<<<HQ / 4, 256, 0, stream>>>(W_ih, gi_sel, gh_pre, b_ih, b_hh, x2,
                                      hidden, hnew, out + HNEW_OFF);
    k_scores<<<(VQ + LQ) / 4, 256, 0, stream>>>(Wo_W, Wo_b, T, hnew, score);
    k_final<<<MVQ / 256, 256, 0, stream>>>(score, input_seq, out + OUT1_OFF,
                                           out + PC_OFF);
}

// Round 16
// 123.152 us; speedup vs baseline: 1.4005x; 1.4005x over previous
//
#include <hip/hip_runtime.h>
#include <math.h>

#define LQ 2048
#define EQ 1024
#define HQ 1024
#define DQ 512
#define VQ 32000
#define MVQ 32768

// d_out layout (floats): [out1: 32768][h_new: 1024][attn_w: 2048][prob_c: 2048]
#define OUT1_OFF 0
#define HNEW_OFF 32768
#define AW_OFF   33792
#define PC_OFF   35840

typedef __attribute__((ext_vector_type(8))) short short8_t;
typedef __attribute__((ext_vector_type(8))) unsigned short ushort8_t;
typedef __attribute__((ext_vector_type(4))) float floatx4;

// ---------------- helpers ----------------
__device__ inline float wred(float v) {
    v += __shfl_down(v, 32);
    v += __shfl_down(v, 16);
    v += __shfl_down(v, 8);
    v += __shfl_down(v, 4);
    v += __shfl_down(v, 2);
    v += __shfl_down(v, 1);
    return v;
}
__device__ inline float wred_max(float v) {
    v = fmaxf(v, __shfl_down(v, 32));
    v = fmaxf(v, __shfl_down(v, 16));
    v = fmaxf(v, __shfl_down(v, 8));
    v = fmaxf(v, __shfl_down(v, 4));
    v = fmaxf(v, __shfl_down(v, 2));
    v = fmaxf(v, __shfl_down(v, 1));
    return v;
}
__device__ inline float sigmoidf_(float x) { return 1.0f / (1.0f + expf(-x)); }
__device__ inline unsigned short f2bf(float x) {  // RNE to bf16 bits
    unsigned int u = __float_as_uint(x);
    unsigned int r = (u + 0x7fffu + ((u >> 16) & 1u)) >> 16;
    return (unsigned short)r;
}
__device__ inline float bf2f(unsigned short b) {
    return __uint_as_float(((unsigned int)b) << 16);
}
// async global->LDS, 16B per lane; LDS dest is wave-uniform base + lane*16
__device__ __forceinline__ void gload16(const unsigned short* g,
                                        unsigned short* l) {
    __builtin_amdgcn_global_load_lds(
        (const __attribute__((address_space(1))) unsigned int*)g,
        (__attribute__((address_space(3))) unsigned int*)l, 16, 0, 0);
}

// ---------------- k_prep ----------------
// blocks 0..127   : attn logits (16 rows/block); blocks 0..3 also zero aa
// block  128      : sel_reading (exact int32 truncation) -> x2[1024:2048)
// blocks 129..1664: split enc (2M) then Wc (1M) into bf16 hi/lo
__global__ __launch_bounds__(256) void k_prep(
    const float* __restrict__ enc, const float* __restrict__ Wc,
    const int* __restrict__ inp, const int* __restrict__ input_seq,
    const int* __restrict__ pre_prob,
    const float* __restrict__ attn_W, const float* __restrict__ attn_b,
    const float* __restrict__ emb, const float* __restrict__ hidden,
    unsigned short* __restrict__ Ah, unsigned short* __restrict__ Al,
    unsigned short* __restrict__ Bh, unsigned short* __restrict__ Bl,
    float* __restrict__ x2, float* __restrict__ logits, float* __restrict__ aa)
{
    __shared__ int s_cnt;
    __shared__ int s_list[LQ];
    const int tid = threadIdx.x;
    const int bx = blockIdx.x;
    if (bx < 128) {  // ---- attn logits, 16 rows/block (4/wave) ----
        if (bx < 4) aa[bx * 256 + tid] = 0.0f;
        int warp = tid >> 6, lane = tid & 63;
        int tok = inp[0];
        int ei = (tok >= VQ) ? 2 : tok;
        const float4* e4 = (const float4*)(emb + (size_t)ei * DQ);
        const float4* h4 = (const float4*)hidden;
        #pragma unroll
        for (int rr = 0; rr < 4; ++rr) {
            int r = bx * 16 + warp * 4 + rr;
            const float4* Wr = (const float4*)(attn_W + (size_t)r * 1536);
            float acc = 0.0f;
            #pragma unroll
            for (int i = 0; i < 6; ++i) {
                int idx = lane + i * 64;
                float4 x = (idx < 128) ? e4[idx] : h4[idx - 128];
                float4 w = Wr[idx];
                acc += w.x * x.x + w.y * x.y + w.z * x.z + w.w * x.w;
            }
            acc = wred(acc);
            if (lane == 0) logits[r] = acc + attn_b[r];
        }
        return;
    }
    if (bx == 128) {  // ---- sel_reading ----
        if (tid == 0) s_cnt = 0;
        __syncthreads();
        int tok = inp[0];
        for (int l = tid; l < LQ; l += 256) {
            if (input_seq[l] == tok && pre_prob[l] != 0) {
                int p = atomicAdd(&s_cnt, 1);
                s_list[p] = l;
            }
        }
        __syncthreads();
        int nm = s_cnt;
        for (int e = tid; e < EQ; e += 256) {
            int acc = 0;
            for (int j = 0; j < nm; ++j)
                acc += (int)enc[(size_t)s_list[j] * EQ + e];
            x2[HQ + e] = (float)acc;
        }
        return;
    }
    // ---- bf16 hi/lo split ----
    size_t e0 = ((size_t)(bx - 129) * 256 + tid) * 8;
    const float* src;
    unsigned short *hdst, *ldst;
    size_t off;
    if (e0 < (size_t)LQ * EQ) { src = enc; hdst = Ah; ldst = Al; off = e0; }
    else { src = Wc; hdst = Bh; ldst = Bl; off = e0 - (size_t)LQ * EQ; }
    float4 v0 = *(const float4*)(src + off);
    float4 v1 = *(const float4*)(src + off + 4);
    float vv[8] = {v0.x, v0.y, v0.z, v0.w, v1.x, v1.y, v1.z, v1.w};
    ushort8_t H, L;
    #pragma unroll
    for (int k = 0; k < 8; ++k) {
        float x = vv[k];
        unsigned short hb = f2bf(x);
        H[k] = hb;
        L[k] = f2bf(x - bf2f(hb));  // exact residual
    }
    *(ushort8_t*)(hdst + off) = H;
    *(ushort8_t*)(ldst + off) = L;
}

// ---------------- k_gemm_fused ----------------
// blocks [0,128)   : T[l][h] = tanh(enc[l,:].Wc[h,:] + Wc_b[h]).
//                    128x128 tile (4x less HBM over-fetch than 64x64:
//                    measured 225 MB FETCH was the 40us bottleneck),
//                    XCD m-group swizzle (each XCD owns 2 m-stripes x all
//                    n-tiles -> A-stripes L2-resident), BK=32 dbuf 64KB,
//                    4 waves x 64x64 quadrant, 48 MFMA + 16 ds_read/barrier.
// blocks [128,192) : attn softmax + apply -> aa (+ aw output)
// blocks [192,384) : gi_sel  (16 rows/block, 3072 rows)
// blocks [384,576) : gh_pre  (16 rows/block, 3072 rows)
// blocks [576,640) : pre_c   (16 rows/block, 1024 rows)
// 640 blocks at 2/CU (64KB LDS) -> gemm + aux co-resident (overlap).
__global__ __launch_bounds__(256, 2) void k_gemm_fused(
    const unsigned short* __restrict__ Ah, const unsigned short* __restrict__ Al,
    const unsigned short* __restrict__ Bh, const unsigned short* __restrict__ Bl,
    float* __restrict__ T, const float* __restrict__ Wc_b,
    const float* __restrict__ logits, const float* __restrict__ enc,
    float* __restrict__ aa, float* __restrict__ aw_out,
    const float* __restrict__ W_ih, const float* __restrict__ W_hh,
    const float* __restrict__ comb_W, const int* __restrict__ inp,
    const float* __restrict__ emb, const float* __restrict__ hidden,
    const float* __restrict__ x2,
    float* __restrict__ gi_sel, float* __restrict__ gh_pre,
    float* __restrict__ pre_c)
{
    // 2 buffers x 4 arrays x 128 rows x 32 bf16 = 64 KB -> 2 blocks/CU
    __shared__ unsigned short sm[2 * 4 * 4096];
    const int b = blockIdx.x, t = threadIdx.x;
    const int lane = t & 63, wid = t >> 6;

    if (b < 128) {  // =================== GEMM -> T ===================
        // XCD-locality swizzle: XCD x (= b%8) processes m-groups {2x,2x+1},
        // all 8 n-tiles each. A m-stripe stays in that XCD's L2.
        const int xcd = b & 7, kk_ = b >> 3;           // kk_ in [0,16)
        const int m0 = (xcd * 2 + (kk_ >> 3)) * 128;   // 16 m-tiles
        const int n0 = (kk_ & 7) * 128;                // 8 n-tiles
        const unsigned short* tsrc =
            (wid == 0) ? Ah + (size_t)m0 * EQ :
            (wid == 1) ? Al + (size_t)m0 * EQ :
            (wid == 2) ? Bh + (size_t)n0 * EQ :
                         Bl + (size_t)n0 * EQ;
        const int srow = lane >> 2;     // 0..15: row within 16-row call
        const int schunk = lane & 3;    // 0..3: 16B chunk within 64B row
        const int wm = (wid >> 1) * 64, wn = (wid & 1) * 64;
        const int fr = lane & 15, kg = lane >> 4;

        floatx4 acc[4][4];
        #pragma unroll
        for (int i = 0; i < 4; ++i)
            #pragma unroll
            for (int j = 0; j < 4; ++j)
                acc[i][j] = (floatx4){0.f, 0.f, 0.f, 0.f};

        // wave stages its 128x32 tile into buffer `buf` for K-step s.
        // LDS linear [row][4 chunks]; global source pre-swizzled by the
        // involution chunk^((row>>1)&3) that the read side applies.
        #define STAGE(buf, s)                                                  \
            {                                                                  \
                unsigned short* dst = sm + (buf) * 16384 + wid * 4096;         \
                _Pragma("unroll")                                              \
                for (int c = 0; c < 8; ++c) {                                  \
                    int row = c * 16 + srow;                                   \
                    int gch = schunk ^ ((row >> 1) & 3);                       \
                    gload16(tsrc + (size_t)row * EQ + (s) * 32 + gch * 8,      \
                            dst + c * 512);                                    \
                }                                                              \
            }

        STAGE(0, 0);
        __syncthreads();  // vmcnt(0) drain by compiler
        for (int s = 0; s < 32; ++s) {
            int cur = s & 1;
            if (s < 31) STAGE(cur ^ 1, s + 1);  // async, overlaps compute
            const char* base = (const char*)sm + cur * 32768;
            short8_t fah[4], fal[4], fbh[4], fbl[4];
            #pragma unroll
            for (int f = 0; f < 4; ++f) {
                int ra = wm + f * 16 + fr;
                int oa = ra * 64 + ((kg ^ ((ra >> 1) & 3)) * 16);
                fah[f] = *(const short8_t*)(base + oa);
                fal[f] = *(const short8_t*)(base + 8192 + oa);
                int rb = wn + f * 16 + fr;
                int ob = rb * 64 + ((kg ^ ((rb >> 1) & 3)) * 16);
                fbh[f] = *(const short8_t*)(base + 16384 + ob);
                fbl[f] = *(const short8_t*)(base + 24576 + ob);
            }
            #pragma unroll
            for (int i = 0; i < 4; ++i)
                #pragma unroll
                for (int j = 0; j < 4; ++j) {
                    acc[i][j] = __builtin_amdgcn_mfma_f32_16x16x32_bf16(
                        fah[i], fbh[j], acc[i][j], 0, 0, 0);
                    acc[i][j] = __builtin_amdgcn_mfma_f32_16x16x32_bf16(
                        fal[i], fbh[j], acc[i][j], 0, 0, 0);
                    acc[i][j] = __builtin_amdgcn_mfma_f32_16x16x32_bf16(
                        fah[i], fbl[j], acc[i][j], 0, 0, 0);
                }
            __syncthreads();  // drains next-stage loads + guards buffer reuse
        }
        // epilogue: tanh(acc + bias) -> T.  C/D: col=lane&15, row=(lane>>4)*4+r
        #pragma unroll
        for (int i = 0; i < 4; ++i)
            #pragma unroll
            for (int j = 0; j < 4; ++j) {
                int row = m0 + wm + i * 16 + kg * 4;
                int col = n0 + wn + j * 16 + fr;
                float bj = Wc_b[col];
                #pragma unroll
                for (int r = 0; r < 4; ++r)
                    T[(size_t)(row + r) * HQ + col] = tanhf(acc[i][j][r] + bj);
            }
        return;
    }
    if (b < 192) {  // =============== attn softmax + apply ===============
        float* sred = (float*)sm;        // alias onto gemm LDS
        float* s_w  = (float*)sm + 8;
        int sb = b - 128;
        int xb = sb & 3, yb = sb >> 2;
        float m = -3.4e38f;
        for (int i = t; i < LQ; i += 256) m = fmaxf(m, logits[i]);
        m = wred_max(m);
        if (lane == 0) sred[wid] = m;
        __syncthreads();
        if (t == 0)
            sred[0] = fmaxf(fmaxf(sred[0], sred[1]), fmaxf(sred[2], sred[3]));
        __syncthreads();
        m = sred[0];
        __syncthreads();
        float s = 0.0f;
        for (int i = t; i < LQ; i += 256) s += expf(logits[i] - m);
        s = wred(s);
        if (lane == 0) sred[wid] = s;
        __syncthreads();
        if (t == 0) sred[0] = sred[0] + sred[1] + sred[2] + sred[3];
        __syncthreads();
        s = sred[0];
        int l0 = yb * 128;
        if (t < 128) {
            float w = expf(logits[l0 + t] - m) / s;
            s_w[t] = w;
            if (xb == 0) aw_out[l0 + t] = w;
        }
        __syncthreads();
        int e = xb * 256 + t;
        float acc = 0.0f;
        for (int l = 0; l < 128; ++l)
            acc = fmaf(s_w[l], enc[(size_t)(l0 + l) * EQ + e], acc);
        atomicAdd(&aa[e], acc);
        return;
    }
    if (b < 384) {  // =============== gi_sel (16 rows/block) ===============
        const float4* xs = (const float4*)(x2 + HQ);
        #pragma unroll
        for (int rr = 0; rr < 4; ++rr) {
            int row = (b - 192) * 16 + wid * 4 + rr;  // [0, 3072)
            const float4* Wr = (const float4*)(W_ih + (size_t)row * 2048 + 1024);
            float acc = 0.0f;
            #pragma unroll
            for (int c = 0; c < 4; ++c) {
                int idx = lane + c * 64;
                float4 w = Wr[idx], x = xs[idx];
                acc += w.x * x.x + w.y * x.y + w.z * x.z + w.w * x.w;
            }
            acc = wred(acc);
            if (lane == 0) gi_sel[row] = acc;
        }
        return;
    }
    if (b < 576) {  // =============== gh_pre (16 rows/block) ===============
        const float4* hv = (const float4*)hidden;
        #pragma unroll
        for (int rr = 0; rr < 4; ++rr) {
            int row = (b - 384) * 16 + wid * 4 + rr;  // [0, 3072)
            const float4* Wr = (const float4*)(W_hh + (size_t)row * 1024);
            float acc = 0.0f;
            #pragma unroll
            for (int c = 0; c < 4; ++c) {
                int idx = lane + c * 64;
                float4 w = Wr[idx], x = hv[idx];
                acc += w.x * x.x + w.y * x.y + w.z * x.z + w.w * x.w;
            }
            acc = wred(acc);
            if (lane == 0) gh_pre[row] = acc;
        }
        return;
    }
    {  // =============== pre_c (16 rows/block) ===============
        int tok = inp[0];
        int ei = (tok >= VQ) ? 2 : tok;
        const float4* e4 = (const float4*)(emb + (size_t)ei * DQ);
        #pragma unroll
        for (int rr = 0; rr < 4; ++rr) {
            int row = (b - 576) * 16 + wid * 4 + rr;  // [0, 1024)
            const float4* Wr = (const float4*)(comb_W + (size_t)row * 1536);
            float acc = 0.0f;
            #pragma unroll
            for (int c = 0; c < 2; ++c) {
                int idx = lane + c * 64;
                float4 w = Wr[idx], x = e4[idx];
                acc += w.x * x.x + w.y * x.y + w.z * x.z + w.w * x.w;
            }
            acc = wred(acc);
            if (lane == 0) pre_c[row] = acc;
        }
        return;
    }
}

// ---------------- k_comb ----------------
// x2[r] = relu(pre_c[r] + comb_W[r,512:1536].aa + comb_b[r])
__global__ __launch_bounds__(256) void k_comb(
    const float* __restrict__ W, const float* __restrict__ b,
    const float* __restrict__ pre_c, const float* __restrict__ aa,
    float* __restrict__ x2)
{
    int warp = threadIdx.x >> 6, lane = threadIdx.x & 63;
    int r = blockIdx.x * 4 + warp;
    const float4* Wr = (const float4*)(W + (size_t)r * 1536 + 512);
    const float4* a4 = (const float4*)aa;
    float acc = 0.0f;
    #pragma unroll
    for (int i = 0; i < 4; ++i) {
        int idx = lane + i * 64;
        float4 w = Wr[idx], x = a4[idx];
        acc += w.x * x.x + w.y * x.y + w.z * x.z + w.w * x.w;
    }
    acc = wred(acc);
    if (lane == 0) x2[r] = fmaxf(acc + pre_c[r] + b[r], 0.0f);
}

// ---------------- k_gru ----------------
// Wave per gate index i: dot the comb-half of the 3 W_ih rows; add
// precomputed gi_sel / gh_pre; gates; h_new.
__global__ __launch_bounds__(256) void k_gru(
    const float* __restrict__ W_ih, const float* __restrict__ gi_sel,
    const float* __restrict__ gh_pre,
    const float* __restrict__ b_ih, const float* __restrict__ b_hh,
    const float* __restrict__ x2, const float* __restrict__ h,
    float* __restrict__ hnew, float* __restrict__ out_h)
{
    int warp = threadIdx.x >> 6, lane = threadIdx.x & 63;
    int i = blockIdx.x * 4 + warp;
    const float4* xv = (const float4*)x2;
    const float4* Wr = (const float4*)(W_ih + (size_t)i * 2048);
    const float4* Wz = (const float4*)(W_ih + (size_t)(HQ + i) * 2048);
    const float4* Wn = (const float4*)(W_ih + (size_t)(2 * HQ + i) * 2048);
    float ar = 0, az = 0, an = 0;
    #pragma unroll
    for (int c = 0; c < 4; ++c) {
        int idx = lane + c * 64;
        float4 x = xv[idx];
        float4 w = Wr[idx]; ar += w.x*x.x + w.y*x.y + w.z*x.z + w.w*x.w;
        w = Wz[idx];        az += w.x*x.x + w.y*x.y + w.z*x.z + w.w*x.w;
        w = Wn[idx];        an += w.x*x.x + w.y*x.y + w.z*x.z + w.w*x.w;
    }
    ar = wred(ar); az = wred(az); an = wred(an);
    if (lane == 0) {
        float gir = ar + gi_sel[i] + b_ih[i];
        float giz = az + gi_sel[HQ + i] + b_ih[HQ + i];
        float gin = an + gi_sel[2 * HQ + i] + b_ih[2 * HQ + i];
        float ghr = gh_pre[i] + b_hh[i];
        float ghz = gh_pre[HQ + i] + b_hh[HQ + i];
        float ghn = gh_pre[2 * HQ + i] + b_hh[2 * HQ + i];
        float r = sigmoidf_(gir + ghr);
        float z = sigmoidf_(giz + ghz);
        float n = tanhf(gin + r * ghn);
        float hn = (1.0f - z) * n + z * h[i];
        hnew[i] = hn;
        out_h[i] = hn;
    }
}

// ---------------- k_scores ----------------
// Unified: r < VQ rows come from Wo_W (+bias), r >= VQ rows come from T
// (tanh already applied in the gemm epilogue). One wave per row.
__global__ __launch_bounds__(256) void k_scores(
    const float* __restrict__ Wo_W, const float* __restrict__ Wo_b,
    const float* __restrict__ T, const float* __restrict__ hnew,
    float* __restrict__ score)
{
    int warp = threadIdx.x >> 6, lane = threadIdx.x & 63;
    int r = blockIdx.x * 4 + warp;
    const float4* hv = (const float4*)hnew;
    const float* Wr = (r < VQ) ? Wo_W + (size_t)r * HQ
                               : T + (size_t)(r - VQ) * HQ;
    const float4* W4 = (const float4*)Wr;
    float acc = 0.0f;
    #pragma unroll
    for (int i = 0; i < 4; ++i) {
        int idx = lane + i * 64;
        float4 w = W4[idx], x = hv[idx];
        acc += w.x * x.x + w.y * x.y + w.z * x.z + w.w * x.w;
    }
    acc = wred(acc);
    if (lane == 0) score[r] = acc + ((r < VQ) ? Wo_b[r] : 0.0f);
}

// ---------------- k_final ----------------
// 128 blocks: per-block recompute of softmax stats (deterministic), LDS-bin
// scatter for the block's 256-wide out1 slice, then log with 1e-9 rules.
__global__ __launch_bounds__(256) void k_final(
    const float* __restrict__ score, const int* __restrict__ input_seq,
    float* __restrict__ out1, float* __restrict__ out_pc)
{
    __shared__ float sred[4];
    __shared__ float bins[256];
    const int N = VQ + LQ;
    int tid = threadIdx.x, wid = tid >> 6, lane = tid & 63;
    float m = -3.4e38f;
    for (int i = tid; i < N; i += 256) m = fmaxf(m, score[i]);
    m = wred_max(m);
    if (lane == 0) sred[wid] = m;
    __syncthreads();
    if (tid == 0)
        sred[0] = fmaxf(fmaxf(sred[0], sred[1]), fmaxf(sred[2], sred[3]));
    __syncthreads();
    m = sred[0];
    __syncthreads();
    float s = 0.0f;
    for (int i = tid; i < N; i += 256) s += expf(score[i] - m);
    s = wred(s);
    if (lane == 0) sred[wid] = s;
    __syncthreads();
    if (tid == 0) sred[0] = sred[0] + sred[1] + sred[2] + sred[3];
    __syncthreads();
    s = sred[0];
    bins[tid] = 0.0f;
    __syncthreads();
    int i0 = blockIdx.x * 256;
    for (int l = tid; l < LQ; l += 256) {
        int si = input_seq[l];
        if (si >= i0 && si < i0 + 256)
            atomicAdd(&bins[si - i0], expf(score[VQ + l] - m) / s);
    }
    if (blockIdx.x < 8) {
        int l = blockIdx.x * 256 + tid;
        out_pc[l] = expf(score[VQ + l] - m) / s;
    }
    __syncthreads();
    int i = i0 + tid;
    float v = ((i < VQ) ? expf(score[i] - m) / s : 0.0f) + bins[tid];
    if (i == 2 || v == 0.0f) v = 1e-9f;
    out1[i] = logf(v);
}

// ---------------- host launch ----------------
extern "C" void kernel_launch(void* const* d_in, const int* in_sizes, int n_in,
                              void* d_out, int out_size, void* d_ws, size_t ws_size,
                              hipStream_t stream) {
    const int*   inp       = (const int*)  d_in[0];
    const float* hidden    = (const float*)d_in[1];
    const float* enc       = (const float*)d_in[2];
    const int*   input_seq = (const int*)  d_in[3];
    const int*   pre_prob  = (const int*)  d_in[4];
    const float* emb       = (const float*)d_in[5];
    const float* attn_W    = (const float*)d_in[6];
    const float* attn_b    = (const float*)d_in[7];
    const float* comb_W    = (const float*)d_in[8];
    const float* comb_b    = (const float*)d_in[9];
    const float* W_ih      = (const float*)d_in[10];
    const float* W_hh      = (const float*)d_in[11];
    const float* b_ih      = (const float*)d_in[12];
    const float* b_hh      = (const float*)d_in[13];
    const float* Wo_W      = (const float*)d_in[14];
    const float* Wo_b      = (const float*)d_in[15];
    const float* Wc_W      = (const float*)d_in[16];
    const float* Wc_b      = (const float*)d_in[17];

    float* out = (float*)d_out;

    // ws: [Ah 2M us][Al 2M us][Bh 1M us][Bl 1M us][T 2M f][smalls]
    unsigned short* Ah = (unsigned short*)d_ws;
    unsigned short* Al = Ah + (size_t)LQ * EQ;
    unsigned short* Bh = Al + (size_t)LQ * EQ;
    unsigned short* Bl = Bh + (size_t)HQ * EQ;
    float* T      = (float*)(Bl + (size_t)HQ * EQ);
    float* x2     = T + (size_t)LQ * HQ;       // 2048 (comb out | sel_reading)
    float* hnew   = x2 + 2048;                 // 1024
    float* logits = hnew + 1024;               // 2048
    float* aa     = logits + 2048;             // 1024
    float* score  = aa + 1024;                 // 34048
    float* gi_sel = score + 34048;             // 3072
    float* gh_pre = gi_sel + 3072;             // 3072
    float* pre_c  = gh_pre + 3072;             // 1024

    k_prep<<<1665, 256, 0, stream>>>(enc, Wc_W, inp, input_seq, pre_prob,
                                     attn_W, attn_b, emb, hidden,
                                     Ah, Al, Bh, Bl, x2, logits, aa);
    k_gemm_fused<<<640, 256, 0, stream>>>(Ah, Al, Bh, Bl, T, Wc_b, logits,
                                          enc, aa, out + AW_OFF, W_ih, W_hh,
                                          comb_W, inp, emb, hidden, x2,
                                          gi_sel, gh_pre, pre_c);
    k_comb<<<HQ / 4, 256, 0, stream>>>(comb_W, comb_b, pre_c, aa, x2);
    k_gru<<<HQ / 4, 256, 0, stream>>>(W_ih, gi_sel, gh_pre, b_ih, b_hh, x2,
                                      hidden, hnew, out + HNEW_OFF);
    k_scores<<<(VQ + LQ) / 4, 256, 0, stream>>>(Wo_W, Wo_b, T, hnew, score);
    k_final<<<MVQ / 256, 256, 0, stream>>>(score, input_seq, out + OUT1_OFF,
                                           out + PC_OFF);
}

// Round 17
// 110.657 us; speedup vs baseline: 1.5586x; 1.1129x over previous
//
#include <hip/hip_runtime.h>
#include <math.h>

#define LQ 2048
#define EQ 1024
#define HQ 1024
#define DQ 512
#define VQ 32000
#define MVQ 32768

// d_out layout (floats): [out1: 32768][h_new: 1024][attn_w: 2048][prob_c: 2048]
#define OUT1_OFF 0
#define HNEW_OFF 32768
#define AW_OFF   33792
#define PC_OFF   35840

typedef __attribute__((ext_vector_type(8))) short short8_t;
typedef __attribute__((ext_vector_type(8))) unsigned short ushort8_t;
typedef __attribute__((ext_vector_type(4))) float floatx4;

// ---------------- helpers ----------------
__device__ inline float wred(float v) {
    v += __shfl_down(v, 32);
    v += __shfl_down(v, 16);
    v += __shfl_down(v, 8);
    v += __shfl_down(v, 4);
    v += __shfl_down(v, 2);
    v += __shfl_down(v, 1);
    return v;
}
__device__ inline float wred_max(float v) {
    v = fmaxf(v, __shfl_down(v, 32));
    v = fmaxf(v, __shfl_down(v, 16));
    v = fmaxf(v, __shfl_down(v, 8));
    v = fmaxf(v, __shfl_down(v, 4));
    v = fmaxf(v, __shfl_down(v, 2));
    v = fmaxf(v, __shfl_down(v, 1));
    return v;
}
__device__ inline float sigmoidf_(float x) { return 1.0f / (1.0f + expf(-x)); }
__device__ inline unsigned short f2bf(float x) {  // RNE to bf16 bits
    unsigned int u = __float_as_uint(x);
    unsigned int r = (u + 0x7fffu + ((u >> 16) & 1u)) >> 16;
    return (unsigned short)r;
}
__device__ inline float bf2f(unsigned short b) {
    return __uint_as_float(((unsigned int)b) << 16);
}
// async global->LDS, 16B per lane; LDS dest is wave-uniform base + lane*16
__device__ __forceinline__ void gload16(const unsigned short* g,
                                        unsigned short* l) {
    __builtin_amdgcn_global_load_lds(
        (const __attribute__((address_space(1))) unsigned int*)g,
        (__attribute__((address_space(3))) unsigned int*)l, 16, 0, 0);
}

// ---------------- k_prep ----------------
// blocks 0..511   : attn logits (4 rows/block); blocks 0..3 also zero aa
// block  512      : sel_reading (exact int32 truncation) -> x2[1024:2048)
// blocks 513..2048: split enc (2M) then Wc (1M) into bf16 hi/lo
__global__ __launch_bounds__(256) void k_prep(
    const float* __restrict__ enc, const float* __restrict__ Wc,
    const int* __restrict__ inp, const int* __restrict__ input_seq,
    const int* __restrict__ pre_prob,
    const float* __restrict__ attn_W, const float* __restrict__ attn_b,
    const float* __restrict__ emb, const float* __restrict__ hidden,
    unsigned short* __restrict__ Ah, unsigned short* __restrict__ Al,
    unsigned short* __restrict__ Bh, unsigned short* __restrict__ Bl,
    float* __restrict__ x2, float* __restrict__ logits, float* __restrict__ aa)
{
    __shared__ int s_cnt;
    __shared__ int s_list[LQ];
    const int tid = threadIdx.x;
    const int bx = blockIdx.x;
    if (bx < 512) {  // ---- attn logits ----
        if (bx < 4) aa[bx * 256 + tid] = 0.0f;
        int warp = tid >> 6, lane = tid & 63;
        int r = bx * 4 + warp;
        int tok = inp[0];
        int ei = (tok >= VQ) ? 2 : tok;
        const float4* Wr = (const float4*)(attn_W + (size_t)r * 1536);
        const float4* e4 = (const float4*)(emb + (size_t)ei * DQ);
        const float4* h4 = (const float4*)hidden;
        float acc = 0.0f;
        #pragma unroll
        for (int i = 0; i < 6; ++i) {
            int idx = lane + i * 64;
            float4 x = (idx < 128) ? e4[idx] : h4[idx - 128];
            float4 w = Wr[idx];
            acc += w.x * x.x + w.y * x.y + w.z * x.z + w.w * x.w;
        }
        acc = wred(acc);
        if (lane == 0) logits[r] = acc + attn_b[r];
        return;
    }
    if (bx == 512) {  // ---- sel_reading ----
        if (tid == 0) s_cnt = 0;
        __syncthreads();
        int tok = inp[0];
        for (int l = tid; l < LQ; l += 256) {
            if (input_seq[l] == tok && pre_prob[l] != 0) {
                int p = atomicAdd(&s_cnt, 1);
                s_list[p] = l;
            }
        }
        __syncthreads();
        int nm = s_cnt;
        for (int e = tid; e < EQ; e += 256) {
            int acc = 0;
            for (int j = 0; j < nm; ++j)
                acc += (int)enc[(size_t)s_list[j] * EQ + e];
            x2[HQ + e] = (float)acc;
        }
        return;
    }
    // ---- bf16 hi/lo split ----
    size_t e0 = ((size_t)(bx - 513) * 256 + tid) * 8;
    const float* src;
    unsigned short *hdst, *ldst;
    size_t off;
    if (e0 < (size_t)LQ * EQ) { src = enc; hdst = Ah; ldst = Al; off = e0; }
    else { src = Wc; hdst = Bh; ldst = Bl; off = e0 - (size_t)LQ * EQ; }
    float4 v0 = *(const float4*)(src + off);
    float4 v1 = *(const float4*)(src + off + 4);
    float vv[8] = {v0.x, v0.y, v0.z, v0.w, v1.x, v1.y, v1.z, v1.w};
    ushort8_t H, L;
    #pragma unroll
    for (int k = 0; k < 8; ++k) {
        float x = vv[k];
        unsigned short hb = f2bf(x);
        H[k] = hb;
        L[k] = f2bf(x - bf2f(hb));  // exact residual
    }
    *(ushort8_t*)(hdst + off) = H;
    *(ushort8_t*)(ldst + off) = L;
}

// ---------------- k_gemm_fused ----------------
// blocks [0,512)     : T[l][h] = tanh(enc[l,:].Wc[h,:] + Wc_b[h]) directly.
//   64x64 tile, full K=1024, BK=32 double-buffered, 4 blocks/CU.
//   XCD-REGION TILE MAP (this round's single change): round-15 diagnostic
//   measured 225 MB of L2-miss traffic (19.4 TB/s realized = L3 path, not
//   HBM) on a 12 MB working set -> cross-XCD L2 thrash. XCD x (= b&7 under
//   round-robin dispatch) now owns an 8m x 8n tile region: footprint
//   2 MB (A-stripes) + 2 MB (B-cols) = 4 MB = exactly one XCD's L2.
// blocks [512,576)   : attn softmax + apply -> aa (+ aw output)
// blocks [576,1344)  : gi_sel[r] = W_ih[r,1024:2048] . sel       (3072 rows)
// blocks [1344,2112) : gh_pre[r] = W_hh[r,:] . hidden            (3072 rows)
// blocks [2112,2368) : pre_c[r]  = comb_W[r,0:512] . emb_row     (1024 rows)
__global__ __launch_bounds__(256, 4) void k_gemm_fused(
    const unsigned short* __restrict__ Ah, const unsigned short* __restrict__ Al,
    const unsigned short* __restrict__ Bh, const unsigned short* __restrict__ Bl,
    float* __restrict__ T, const float* __restrict__ Wc_b,
    const float* __restrict__ logits, const float* __restrict__ enc,
    float* __restrict__ aa, float* __restrict__ aw_out,
    const float* __restrict__ W_ih, const float* __restrict__ W_hh,
    const float* __restrict__ comb_W, const int* __restrict__ inp,
    const float* __restrict__ emb, const float* __restrict__ hidden,
    const float* __restrict__ x2,
    float* __restrict__ gi_sel, float* __restrict__ gh_pre,
    float* __restrict__ pre_c)
{
    // 2 buffers x 4 arrays x 64 rows x 32 bf16 = 32 KB -> 4 blocks/CU
    __shared__ unsigned short sm[2 * 4 * 2048];
    const int b = blockIdx.x, t = threadIdx.x;
    const int lane = t & 63, wid = t >> 6;

    if (b < 512) {  // =================== GEMM -> T ===================
        // XCD-region map: xcd = b&7 owns m-tiles [8*(xcd>>1), +8) x
        // n-tiles [8*(xcd&1), +8).  i = b>>3 walks the 8x8 region.
        const int xcd = b & 7, i_ = b >> 3;           // i_ in [0,64)
        const int m0 = ((xcd >> 1) * 8 + (i_ & 7)) * 64;   // 32 m-tiles
        const int n0 = ((xcd & 1) * 8 + (i_ >> 3)) * 64;   // 16 n-tiles
        const unsigned short* tsrc =
            (wid == 0) ? Ah + (size_t)m0 * EQ :
            (wid == 1) ? Al + (size_t)m0 * EQ :
            (wid == 2) ? Bh + (size_t)n0 * EQ :
                         Bl + (size_t)n0 * EQ;
        const int srow = lane >> 2, schunk = lane & 3;
        const int wm = (wid >> 1) * 32, wn = (wid & 1) * 32;
        const int fr = lane & 15, kg = lane >> 4;

        floatx4 acc[2][2];
        #pragma unroll
        for (int i = 0; i < 2; ++i)
            #pragma unroll
            for (int j = 0; j < 2; ++j)
                acc[i][j] = (floatx4){0.f, 0.f, 0.f, 0.f};

        // wave stages its 64x32 tile into buffer `buf` for K-step s.
        // LDS linear [row][slot]; source pre-swizzled by the involution
        // slot^((row>>1)&3) that the read side applies.
        #define STAGE(buf, s)                                                  \
            {                                                                  \
                unsigned short* dst = sm + (buf) * 8192 + wid * 2048;          \
                _Pragma("unroll")                                              \
                for (int c = 0; c < 4; ++c) {                                  \
                    int row = c * 16 + srow;                                   \
                    int gch = schunk ^ ((row >> 1) & 3);                       \
                    gload16(tsrc + (size_t)row * EQ + (s) * 32 + gch * 8,      \
                            dst + c * 512);                                    \
                }                                                              \
            }

        STAGE(0, 0);
        __syncthreads();  // vmcnt(0) drain by compiler
        for (int s = 0; s < 32; ++s) {
            int cur = s & 1;
            if (s < 31) STAGE(cur ^ 1, s + 1);  // async, overlaps compute
            const char* base = (const char*)sm + cur * 16384;
            short8_t fah[2], fal[2], fbh[2], fbl[2];
            #pragma unroll
            for (int f = 0; f < 2; ++f) {
                int ra = wm + f * 16 + fr;
                int oa = ra * 64 + ((kg ^ ((ra >> 1) & 3)) * 16);
                fah[f] = *(const short8_t*)(base + oa);
                fal[f] = *(const short8_t*)(base + 4096 + oa);
                int rb = wn + f * 16 + fr;
                int ob = rb * 64 + ((kg ^ ((rb >> 1) & 3)) * 16);
                fbh[f] = *(const short8_t*)(base + 8192 + ob);
                fbl[f] = *(const short8_t*)(base + 12288 + ob);
            }
            #pragma unroll
            for (int i = 0; i < 2; ++i)
                #pragma unroll
                for (int j = 0; j < 2; ++j) {
                    acc[i][j] = __builtin_amdgcn_mfma_f32_16x16x32_bf16(
                        fah[i], fbh[j], acc[i][j], 0, 0, 0);
                    acc[i][j] = __builtin_amdgcn_mfma_f32_16x16x32_bf16(
                        fal[i], fbh[j], acc[i][j], 0, 0, 0);
                    acc[i][j] = __builtin_amdgcn_mfma_f32_16x16x32_bf16(
                        fah[i], fbl[j], acc[i][j], 0, 0, 0);
                }
            __syncthreads();  // drains next-stage loads + guards buffer reuse
        }
        // epilogue: tanh(acc + bias) -> T.  C/D: col=lane&15, row=(lane>>4)*4+r
        #pragma unroll
        for (int i = 0; i < 2; ++i)
            #pragma unroll
            for (int j = 0; j < 2; ++j) {
                int row = m0 + wm + i * 16 + kg * 4;
                int col = n0 + wn + j * 16 + fr;
                float bj = Wc_b[col];
                #pragma unroll
                for (int r = 0; r < 4; ++r)
                    T[(size_t)(row + r) * HQ + col] = tanhf(acc[i][j][r] + bj);
            }
        return;
    }
    if (b < 576) {  // =============== attn softmax + apply ===============
        float* sred = (float*)sm;        // alias onto gemm LDS
        float* s_w  = (float*)sm + 8;
        int sb = b - 512;
        int xb = sb & 3, yb = sb >> 2;
        float m = -3.4e38f;
        for (int i = t; i < LQ; i += 256) m = fmaxf(m, logits[i]);
        m = wred_max(m);
        if (lane == 0) sred[wid] = m;
        __syncthreads();
        if (t == 0)
            sred[0] = fmaxf(fmaxf(sred[0], sred[1]), fmaxf(sred[2], sred[3]));
        __syncthreads();
        m = sred[0];
        __syncthreads();
        float s = 0.0f;
        for (int i = t; i < LQ; i += 256) s += expf(logits[i] - m);
        s = wred(s);
        if (lane == 0) sred[wid] = s;
        __syncthreads();
        if (t == 0) sred[0] = sred[0] + sred[1] + sred[2] + sred[3];
        __syncthreads();
        s = sred[0];
        int l0 = yb * 128;
        if (t < 128) {
            float w = expf(logits[l0 + t] - m) / s;
            s_w[t] = w;
            if (xb == 0) aw_out[l0 + t] = w;
        }
        __syncthreads();
        int e = xb * 256 + t;
        float acc = 0.0f;
        for (int l = 0; l < 128; ++l)
            acc = fmaf(s_w[l], enc[(size_t)(l0 + l) * EQ + e], acc);
        atomicAdd(&aa[e], acc);
        return;
    }
    if (b < 1344) {  // =============== gi_sel ===============
        int row = (b - 576) * 4 + wid;  // [0, 3072)
        const float4* Wr = (const float4*)(W_ih + (size_t)row * 2048 + 1024);
        const float4* xs = (const float4*)(x2 + HQ);
        float acc = 0.0f;
        #pragma unroll
        for (int c = 0; c < 4; ++c) {
            int idx = lane + c * 64;
            float4 w = Wr[idx], x = xs[idx];
            acc += w.x * x.x + w.y * x.y + w.z * x.z + w.w * x.w;
        }
        acc = wred(acc);
        if (lane == 0) gi_sel[row] = acc;
        return;
    }
    if (b < 2112) {  // =============== gh_pre ===============
        int row = (b - 1344) * 4 + wid;  // [0, 3072)
        const float4* Wr = (const float4*)(W_hh + (size_t)row * 1024);
        const float4* hv = (const float4*)hidden;
        float acc = 0.0f;
        #pragma unroll
        for (int c = 0; c < 4; ++c) {
            int idx = lane + c * 64;
            float4 w = Wr[idx], x = hv[idx];
            acc += w.x * x.x + w.y * x.y + w.z * x.z + w.w * x.w;
        }
        acc = wred(acc);
        if (lane == 0) gh_pre[row] = acc;
        return;
    }
    {  // =============== pre_c (comb embedded half) ===============
        int row = (b - 2112) * 4 + wid;  // [0, 1024)
        int tok = inp[0];
        int ei = (tok >= VQ) ? 2 : tok;
        const float4* Wr = (const float4*)(comb_W + (size_t)row * 1536);
        const float4* e4 = (const float4*)(emb + (size_t)ei * DQ);
        float acc = 0.0f;
        #pragma unroll
        for (int c = 0; c < 2; ++c) {
            int idx = lane + c * 64;
            float4 w = Wr[idx], x = e4[idx];
            acc += w.x * x.x + w.y * x.y + w.z * x.z + w.w * x.w;
        }
        acc = wred(acc);
        if (lane == 0) pre_c[row] = acc;
        return;
    }
}

// ---------------- k_comb ----------------
// x2[r] = relu(pre_c[r] + comb_W[r,512:1536].aa + comb_b[r])
__global__ __launch_bounds__(256) void k_comb(
    const float* __restrict__ W, const float* __restrict__ b,
    const float* __restrict__ pre_c, const float* __restrict__ aa,
    float* __restrict__ x2)
{
    int warp = threadIdx.x >> 6, lane = threadIdx.x & 63;
    int r = blockIdx.x * 4 + warp;
    const float4* Wr = (const float4*)(W + (size_t)r * 1536 + 512);
    const float4* a4 = (const float4*)aa;
    float acc = 0.0f;
    #pragma unroll
    for (int i = 0; i < 4; ++i) {
        int idx = lane + i * 64;
        float4 w = Wr[idx], x = a4[idx];
        acc += w.x * x.x + w.y * x.y + w.z * x.z + w.w * x.w;
    }
    acc = wred(acc);
    if (lane == 0) x2[r] = fmaxf(acc + pre_c[r] + b[r], 0.0f);
}

// ---------------- k_gru ----------------
// Wave per gate index i: dot the comb-half of the 3 W_ih rows; add
// precomputed gi_sel / gh_pre; gates; h_new.
__global__ __launch_bounds__(256) void k_gru(
    const float* __restrict__ W_ih, const float* __restrict__ gi_sel,
    const float* __restrict__ gh_pre,
    const float* __restrict__ b_ih, const float* __restrict__ b_hh,
    const float* __restrict__ x2, const float* __restrict__ h,
    float* __restrict__ hnew, float* __restrict__ out_h)
{
    int warp = threadIdx.x >> 6, lane = threadIdx.x & 63;
    int i = blockIdx.x * 4 + warp;
    const float4* xv = (const float4*)x2;
    const float4* Wr = (const float4*)(W_ih + (size_t)i * 2048);
    const float4* Wz = (const float4*)(W_ih + (size_t)(HQ + i) * 2048);
    const float4* Wn = (const float4*)(W_ih + (size_t)(2 * HQ + i) * 2048);
    float ar = 0, az = 0, an = 0;
    #pragma unroll
    for (int c = 0; c < 4; ++c) {
        int idx = lane + c * 64;
        float4 x = xv[idx];
        float4 w = Wr[idx]; ar += w.x*x.x + w.y*x.y + w.z*x.z + w.w*x.w;
        w = Wz[idx];        az += w.x*x.x + w.y*x.y + w.z*x.z + w.w*x.w;
        w = Wn[idx];        an += w.x*x.x + w.y*x.y + w.z*x.z + w.w*x.w;
    }
    ar = wred(ar); az = wred(az); an = wred(an);
    if (lane == 0) {
        float gir = ar + gi_sel[i] + b_ih[i];
        float giz = az + gi_sel[HQ + i] + b_ih[HQ + i];
        float gin = an + gi_sel[2 * HQ + i] + b_ih[2 * HQ + i];
        float ghr = gh_pre[i] + b_hh[i];
        float ghz = gh_pre[HQ + i] + b_hh[HQ + i];
        float ghn = gh_pre[2 * HQ + i] + b_hh[2 * HQ + i];
        float r = sigmoidf_(gir + ghr);
        float z = sigmoidf_(giz + ghz);
        float n = tanhf(gin + r * ghn);
        float hn = (1.0f - z) * n + z * h[i];
        hnew[i] = hn;
        out_h[i] = hn;
    }
}

// ---------------- k_scores ----------------
// Unified: r < VQ rows come from Wo_W (+bias), r >= VQ rows come from T
// (tanh already applied in the gemm epilogue). One wave per row.
__global__ __launch_bounds__(256) void k_scores(
    const float* __restrict__ Wo_W, const float* __restrict__ Wo_b,
    const float* __restrict__ T, const float* __restrict__ hnew,
    float* __restrict__ score)
{
    int warp = threadIdx.x >> 6, lane = threadIdx.x & 63;
    int r = blockIdx.x * 4 + warp;
    const float4* hv = (const float4*)hnew;
    const float* Wr = (r < VQ) ? Wo_W + (size_t)r * HQ
                               : T + (size_t)(r - VQ) * HQ;
    const float4* W4 = (const float4*)Wr;
    float acc = 0.0f;
    #pragma unroll
    for (int i = 0; i < 4; ++i) {
        int idx = lane + i * 64;
        float4 w = W4[idx], x = hv[idx];
        acc += w.x * x.x + w.y * x.y + w.z * x.z + w.w * x.w;
    }
    acc = wred(acc);
    if (lane == 0) score[r] = acc + ((r < VQ) ? Wo_b[r] : 0.0f);
}

// ---------------- k_final ----------------
// 128 blocks: per-block recompute of softmax stats (deterministic), LDS-bin
// scatter for the block's 256-wide out1 slice, then log with 1e-9 rules.
__global__ __launch_bounds__(256) void k_final(
    const float* __restrict__ score, const int* __restrict__ input_seq,
    float* __restrict__ out1, float* __restrict__ out_pc)
{
    __shared__ float sred[4];
    __shared__ float bins[256];
    const int N = VQ + LQ;
    int tid = threadIdx.x, wid = tid >> 6, lane = tid & 63;
    float m = -3.4e38f;
    for (int i = tid; i < N; i += 256) m = fmaxf(m, score[i]);
    m = wred_max(m);
    if (lane == 0) sred[wid] = m;
    __syncthreads();
    if (tid == 0)
        sred[0] = fmaxf(fmaxf(sred[0], sred[1]), fmaxf(sred[2], sred[3]));
    __syncthreads();
    m = sred[0];
    __syncthreads();
    float s = 0.0f;
    for (int i = tid; i < N; i += 256) s += expf(score[i] - m);
    s = wred(s);
    if (lane == 0) sred[wid] = s;
    __syncthreads();
    if (tid == 0) sred[0] = sred[0] + sred[1] + sred[2] + sred[3];
    __syncthreads();
    s = sred[0];
    bins[tid] = 0.0f;
    __syncthreads();
    int i0 = blockIdx.x * 256;
    for (int l = tid; l < LQ; l += 256) {
        int si = input_seq[l];
        if (si >= i0 && si < i0 + 256)
            atomicAdd(&bins[si - i0], expf(score[VQ + l] - m) / s);
    }
    if (blockIdx.x < 8) {
        int l = blockIdx.x * 256 + tid;
        out_pc[l] = expf(score[VQ + l] - m) / s;
    }
    __syncthreads();
    int i = i0 + tid;
    float v = ((i < VQ) ? expf(score[i] - m) / s : 0.0f) + bins[tid];
    if (i == 2 || v == 0.0f) v = 1e-9f;
    out1[i] = logf(v);
}

// ---------------- host launch ----------------
extern "C" void kernel_launch(void* const* d_in, const int* in_sizes, int n_in,
                              void* d_out, int out_size, void* d_ws, size_t ws_size,
                              hipStream_t stream) {
    const int*   inp       = (const int*)  d_in[0];
    const float* hidden    = (const float*)d_in[1];
    const float* enc       = (const float*)d_in[2];
    const int*   input_seq = (const int*)  d_in[3];
    const int*   pre_prob  = (const int*)  d_in[4];
    const float* emb       = (const float*)d_in[5];
    const float* attn_W    = (const float*)d_in[6];
    const float* attn_b    = (const float*)d_in[7];
    const float* comb_W    = (const float*)d_in[8];
    const float* comb_b    = (const float*)d_in[9];
    const float* W_ih      = (const float*)d_in[10];
    const float* W_hh      = (const float*)d_in[11];
    const float* b_ih      = (const float*)d_in[12];
    const float* b_hh      = (const float*)d_in[13];
    const float* Wo_W      = (const float*)d_in[14];
    const float* Wo_b      = (const float*)d_in[15];
    const float* Wc_W      = (const float*)d_in[16];
    const float* Wc_b      = (const float*)d_in[17];

    float* out = (float*)d_out;

    // ws: [Ah 2M us][Al 2M us][Bh 1M us][Bl 1M us][T 2M f][smalls]
    unsigned short* Ah = (unsigned short*)d_ws;
    unsigned short* Al = Ah + (size_t)LQ * EQ;
    unsigned short* Bh = Al + (size_t)LQ * EQ;
    unsigned short* Bl = Bh + (size_t)HQ * EQ;
    float* T      = (float*)(Bl + (size_t)HQ * EQ);
    float* x2     = T + (size_t)LQ * HQ;       // 2048 (comb out | sel_reading)
    float* hnew   = x2 + 2048;                 // 1024
    float* logits = hnew + 1024;               // 2048
    float* aa     = logits + 2048;             // 1024
    float* score  = aa + 1024;                 // 34048
    float* gi_sel = score + 34048;             // 3072
    float* gh_pre = gi_sel + 3072;             // 3072
    float* pre_c  = gh_pre + 3072;             // 1024

    k_prep<<<2049, 256, 0, stream>>>(enc, Wc_W, inp, input_seq, pre_prob,
                                     attn_W, attn_b, emb, hidden,
                                     Ah, Al, Bh, Bl, x2, logits, aa);
    k_gemm_fused<<<2368, 256, 0, stream>>>(Ah, Al, Bh, Bl, T, Wc_b, logits,
                                           enc, aa, out + AW_OFF, W_ih, W_hh,
                                           comb_W, inp, emb, hidden, x2,
                                           gi_sel, gh_pre, pre_c);
    k_comb<<<HQ / 4, 256, 0, stream>>>(comb_W, comb_b, pre_c, aa, x2);
    k_gru<<<HQ / 4, 256, 0, stream>>>(W_ih, gi_sel, gh_pre, b_ih, b_hh, x2,
                                      hidden, hnew, out + HNEW_OFF);
    k_scores<<<(VQ + LQ) / 4, 256, 0, stream>>>(Wo_W, Wo_b, T, hnew, score);
    k_final<<<MVQ / 256, 256, 0, stream>>>(score, input_seq, out + OUT1_OFF,
                                           out + PC_OFF);
}